// Round 2
// baseline (265.451 us; speedup 1.0000x reference)
//
#include <hip/hip_runtime.h>

// HeteroGAT on MI355X. R12:
//   K1 k_prep: unchanged
//   K2 k_fuse: unchanged (GEMM 4:1 scatter interleave, log2e-prescaled scores)
//   K3 k_agg:  latency-MLP rewrite. All-relation metadata hoisted; phase 1
//              computes all scores -> unnormalized w in LDS (6KB/wave) + Z;
//              phase 2 is a pure gather loop with 8-edge double-buffered
//              prefetch that crosses relation boundaries. First payload group
//              issued before phase 1 so its latency hides under score compute.

#define H_ 8
#define D_ 32
#define HD 256
#define NC 10000
#define NS 1024
#define INC 128
#define INS 64
#define ECC 120000
#define ECS 10000
#define ALPHA 0.2f
#define CAP 64

typedef unsigned short u16;
typedef __attribute__((ext_vector_type(8))) short short8;
typedef __attribute__((ext_vector_type(4))) float f32x4;
typedef __attribute__((ext_vector_type(2))) float f32x2;

// ---- ws layout ----
// u16 region (u16 units)
static constexpr size_t WHB_CC = 0;              // 9*NC*HD
static constexpr size_t WHB_CS = 23040000;       // 3*NC*HD
static constexpr size_t WHB_IN = 30720000;       // NS*HD -> end 30982144 u16
// f32 scores (float units)
static constexpr size_t FB0  = 15491072;
static constexpr size_t ASCC = FB0;              // 9*NC*8
static constexpr size_t ADCC = FB0 + 720000;     // 9*NC*8
static constexpr size_t ASCS = FB0 + 1440000;    // 3*NC*8
static constexpr size_t ADCS = FB0 + 1680000;    // 3*NS*8 -> FB0+1704576
static constexpr size_t BAF  = FB0 + 1704576;    // 4*64 folded bias dots
// bf16 feats + transposed weights (u16 units)
static constexpr size_t FBC  = 34437760;         // 3*NC*128
static constexpr size_t FBS  = 38277760;         // NS*64
static constexpr size_t WTCC = 38343296;         // 9*32768
static constexpr size_t WTCS = 38638208;         // 3*32768
static constexpr size_t WTIN = 38736512;         // 256*64
static constexpr size_t WAT  = 38752896;         // 4*8192 folded attn mats [col][k]
// int counters (byte offset): 93072 ints = 9*NC (cc) then 3*NS (cs)
static constexpr size_t IBYTE = 77768704;
// u16 slots (byte offset): slot for counter c is slt[c*CAP + p]
static constexpr size_t SBYTE = 78140992;

static constexpr int TOTE  = 9 * ECC + 3 * ECS;  // 1,110,000
static constexpr int NB_Z0 = 91;                 // zero: 93072 ints / (int4*256)
static constexpr int NB_FT = 3814;               // feat cvt
static constexpr int NB_WT = 104;                // weight transpose: 13 mats x 8
static constexpr int NB_FO = 32;                 // attn fold: 4 tiles x 8 col-groups
static constexpr int NB_K2 = 2710;               // 542 scatter (g%5==4) + 2168 gemm slots (2157 used)

__device__ __forceinline__ u16 f2b(float f) {
  unsigned u = __float_as_uint(f);
  return (u16)((u + 0x7FFFu + ((u >> 16) & 1u)) >> 16);
}
__device__ __forceinline__ float bl(unsigned u) { return __uint_as_float(u << 16); }
__device__ __forceinline__ float bh(unsigned u) { return __uint_as_float(u & 0xffff0000u); }

// ================= K1: zero + cvt_feat + cvt_w + fold(32) =================
__global__ __launch_bounds__(256) void k_prep(
    const float* f1, const float* f2, const float* f3, const float* fs,
    const float* Wcc, const float* Wcs, const float* Win, const float* Wnode,
    const float* bcc, const float* bnode, const float* bcs, const float* bin,
    const float* accv, const float* acsv,
    u16* wsu, float* wsf, int* cnts) {
  __shared__ float Ls[64 * 65];
  int b = blockIdx.x, t = threadIdx.x;
  if (b < NB_Z0) {                                 // ---- zero counters ----
    int i = b * 256 + t;
    if (i < 23268) ((int4*)cnts)[i] = make_int4(0, 0, 0, 0);
    return;
  }
  b -= NB_Z0;
  if (b < NB_FT) {                                 // ---- f32 -> bf16 feats ----
    const float* src; u16* dst; int idx, n4;
    if (b < 3750) {
      int ty = b / 1250;
      src = (ty == 0) ? f1 : (ty == 1) ? f2 : f3;
      dst = wsu + FBC + (size_t)ty * 1280000;
      idx = (b - ty * 1250) * 256 + t; n4 = 320000;
    } else {
      src = fs; dst = wsu + FBS; idx = (b - 3750) * 256 + t; n4 = 16384;
    }
    if (idx < n4) {
      float4 v = ((const float4*)src)[idx];
      uint2 o;
      o.x = (unsigned)f2b(v.x) | ((unsigned)f2b(v.y) << 16);
      o.y = (unsigned)f2b(v.z) | ((unsigned)f2b(v.w) << 16);
      *(uint2*)(dst + (size_t)idx * 4) = o;
    }
    return;
  }
  b -= NB_FT;
  if (b < NB_WT) {                                 // ---- weight transpose, LDS tile ----
    int mat = b >> 3, sub = b & 7;                 // mat 0..12
    int K = (mat == 12) ? INS : INC;
    if (mat == 12 && sub >= 4) return;
    int k0 = (sub >> 2) * 64, n0 = (sub & 3) * 64;
    const float* src; u16* dst;
    if (mat < 9)        { src = Wcc + (size_t)mat * INC * HD;        dst = wsu + WTCC + (size_t)mat * 32768; }
    else if (mat < 12)  { src = Wcs + (size_t)(mat - 9) * INC * HD;  dst = wsu + WTCS + (size_t)(mat - 9) * 32768; }
    else                { src = Win;                                 dst = wsu + WTIN; }
    #pragma unroll
    for (int it = 0; it < 4; it++) {
      int idx = t + it * 256;
      int r = idx >> 4, c4 = idx & 15;
      float4 v = *(const float4*)&src[(size_t)(k0 + r) * HD + n0 + c4 * 4];
      Ls[r * 65 + c4 * 4 + 0] = v.x; Ls[r * 65 + c4 * 4 + 1] = v.y;
      Ls[r * 65 + c4 * 4 + 2] = v.z; Ls[r * 65 + c4 * 4 + 3] = v.w;
    }
    __syncthreads();
    int n = t >> 2, k8 = (t & 3) * 16;
    unsigned o[8];
    #pragma unroll
    for (int j = 0; j < 8; j++) {
      u16 lo = f2b(Ls[(k8 + 2 * j) * 65 + n]);
      u16 hi = f2b(Ls[(k8 + 2 * j + 1) * 65 + n]);
      o[j] = (unsigned)lo | ((unsigned)hi << 16);
    }
    uint4* dp = (uint4*)&dst[(size_t)(n0 + n) * K + k0 + k8];
    dp[0] = make_uint4(o[0], o[1], o[2], o[3]);
    dp[1] = make_uint4(o[4], o[5], o[6], o[7]);
    return;
  }
  b -= NB_WT;                                      // ---- attn fold: 4 tiles x 8 groups ----
  int tile = b >> 3, sub = b & 7;
  int K = (tile == 3) ? INS : INC;
  int c0 = sub * 8;
  for (int idx = t; idx < 8 * K; idx += 256) {
    int col = c0 + idx / K, k = idx % K;
    int m = col >> 3, h = col & 7;
    const float* W = nullptr; const float* av = nullptr;
    if (tile < 3) {
      if (m < 3)      { int r = 3*tile + m; W = Wcc + (size_t)r*INC*HD;   av = accv + (size_t)r*512 + h*32; }
      else if (m < 6) { int r = 3*(m-3) + tile; W = Wnode + (size_t)tile*INC*HD; av = accv + (size_t)r*512 + 256 + h*32; }
      else if (m == 6){ W = Wcs + (size_t)tile*INC*HD; av = acsv + (size_t)tile*512 + h*32; }
    } else if (m < 3) { W = Win; av = acsv + (size_t)m*512 + 256 + h*32; }
    float s = 0.f;
    if (W) {
      const float* wp = W + (size_t)k * HD + h * 32;
      #pragma unroll 8
      for (int d = 0; d < 32; d++) s += wp[d] * av[d];
    }
    wsu[WAT + (size_t)tile * 8192 + (size_t)col * K + k] = f2b(s);
  }
  if (sub == 0 && t < 64) {
    int col = t, m = col >> 3, h = col & 7;
    const float* bb = nullptr; const float* av = nullptr;
    if (tile < 3) {
      if (m < 3)      { int r = 3*tile + m; bb = bcc + (size_t)r*HD;  av = accv + (size_t)r*512 + h*32; }
      else if (m < 6) { int r = 3*(m-3) + tile; bb = bnode + (size_t)tile*HD; av = accv + (size_t)r*512 + 256 + h*32; }
      else if (m == 6){ bb = bcs + (size_t)tile*HD; av = acsv + (size_t)tile*512 + h*32; }
    } else if (m < 3) { bb = bin; av = acsv + (size_t)m*512 + 256 + h*32; }
    float s = 0.f;
    if (bb) for (int d = 0; d < 32; d++) s += bb[h*32 + d] * av[d];
    wsf[BAF + tile * 64 + col] = s;
  }
}

// ================= K2: interleaved scatter (1 of 5) + GEMMs =================
__global__ __launch_bounds__(256, 2) void k_fuse(
    u16* wsu, float* wsf, const float* bcc, const float* bcs, const float* bin,
    const int* eccs, const int* eccd, const int* ecss, const int* ecsd,
    int* cnts, u16* slt) {
  __shared__ __align__(16) char smem[69632];
  int gb = blockIdx.x, t = threadIdx.x;
  if ((gb % 5) == 4) {                             // ---- edge scatter, 8/thread ----
    int k = gb / 5;                                // 0..541
    int i0 = (k * 256 + t) * 8;
    if (i0 >= TOTE) return;
    int dd[8], ss[8], p[8];
    int cbase;
    if (i0 < 9 * ECC) {
      int r = i0 / ECC;
      int4 d0 = *(const int4*)&eccd[i0]; int4 d1 = *(const int4*)&eccd[i0 + 4];
      int4 s0 = *(const int4*)&eccs[i0]; int4 s1 = *(const int4*)&eccs[i0 + 4];
      dd[0]=d0.x; dd[1]=d0.y; dd[2]=d0.z; dd[3]=d0.w;
      dd[4]=d1.x; dd[5]=d1.y; dd[6]=d1.z; dd[7]=d1.w;
      ss[0]=s0.x; ss[1]=s0.y; ss[2]=s0.z; ss[3]=s0.w;
      ss[4]=s1.x; ss[5]=s1.y; ss[6]=s1.z; ss[7]=s1.w;
      cbase = r * NC;
    } else {
      int u0 = i0 - 9 * ECC;
      int r = u0 / ECS;
      int4 d0 = *(const int4*)&ecsd[u0]; int4 d1 = *(const int4*)&ecsd[u0 + 4];
      int4 s0 = *(const int4*)&ecss[u0]; int4 s1 = *(const int4*)&ecss[u0 + 4];
      dd[0]=d0.x; dd[1]=d0.y; dd[2]=d0.z; dd[3]=d0.w;
      dd[4]=d1.x; dd[5]=d1.y; dd[6]=d1.z; dd[7]=d1.w;
      ss[0]=s0.x; ss[1]=s0.y; ss[2]=s0.z; ss[3]=s0.w;
      ss[4]=s1.x; ss[5]=s1.y; ss[6]=s1.z; ss[7]=s1.w;
      cbase = 90000 + r * NS;
    }
    #pragma unroll
    for (int q = 0; q < 8; q++) p[q] = atomicAdd(&cnts[cbase + dd[q]], 1);
    #pragma unroll
    for (int q = 0; q < 8; q++)
      if (p[q] < CAP) slt[((size_t)(cbase + dd[q])) * CAP + p[q]] = (u16)ss[q];
    return;
  }
  int g = 4 * (gb / 5) + (gb % 5);                 // gemm id 0..2167
  if (g >= 2157) return;
  u16* As = (u16*)smem;
  u16* Bs = (u16*)(smem + 34816);
  const u16 *A, *Bt; const float* bias = nullptr; u16* C = nullptr;
  int M, K, r0, n0 = 0, ty = 0;
  bool isScore = false;
  if (g < 1896) {
    int z = g / 158, rem = g - z * 158;
    int by = rem / 79, bx = rem - by * 79;
    r0 = bx * 128; n0 = by * 128; M = NC; K = 128;
    if (z < 9) { A = wsu + FBC + (size_t)(z/3)*1280000; Bt = wsu + WTCC + (size_t)z*32768; bias = bcc + (size_t)z*HD; C = wsu + WHB_CC + (size_t)z*NC*HD; }
    else { int q = z - 9; A = wsu + FBC + (size_t)q*1280000; Bt = wsu + WTCS + (size_t)q*32768; bias = bcs + (size_t)q*HD; C = wsu + WHB_CS + (size_t)q*NC*HD; }
  } else if (g < 1912) {
    int loc = g - 1896; int by = loc / 8, bx = loc - by * 8;
    r0 = bx * 128; n0 = by * 128; M = NS; K = 64;
    A = wsu + FBS; Bt = wsu + WTIN; bias = bin; C = wsu + WHB_IN;
  } else if (g < 2149) {
    isScore = true; ty = (g - 1912) / 79; int bx = (g - 1912) % 79;
    r0 = bx * 128; M = NC; K = 128;
    A = wsu + FBC + (size_t)ty * 1280000; Bt = wsu + WAT + (size_t)ty * 8192;
  } else {
    isScore = true; ty = 3; int bx = g - 2149;
    r0 = bx * 128; M = NS; K = 64;
    A = wsu + FBS; Bt = wsu + WAT + (size_t)3 * 8192;
  }
  int SA = K + 8;
  int NB = isScore ? 64 : 128;
  {
    int ksh = (K == 128) ? 4 : 3;
    int kmask = (1 << ksh) - 1;
    int sc8 = SA >> 3;
    const uint4* ga = (const uint4*)(A + (size_t)r0 * K);
    const uint4* gb2 = (const uint4*)(Bt + (size_t)n0 * K);
    uint4* la = (uint4*)As; uint4* lb = (uint4*)Bs;
    int tota = (128 * K) >> 3, totb = (NB * K) >> 3;
    for (int i = t; i < tota; i += 256) la[(i >> ksh) * sc8 + (i & kmask)] = ga[i];
    for (int i = t; i < totb; i += 256) lb[(i >> ksh) * sc8 + (i & kmask)] = gb2[i];
  }
  __syncthreads();
  int lane = t & 63, w = t >> 6, l16 = lane & 15, quad = lane >> 4;
  int arow0 = w * 32 + l16;
  if (!isScore) {
    f32x4 acc[2][8];
    #pragma unroll
    for (int i = 0; i < 2; i++)
      #pragma unroll
      for (int j = 0; j < 8; j++) acc[i][j] = (f32x4){0.f, 0.f, 0.f, 0.f};
    for (int ks = 0; ks < K; ks += 32) {
      int ko = ks + quad * 8;
      short8 a0 = *(const short8*)&As[(size_t)arow0 * SA + ko];
      short8 a1 = *(const short8*)&As[(size_t)(arow0 + 16) * SA + ko];
      #pragma unroll
      for (int j = 0; j < 8; j++) {
        short8 bfr = *(const short8*)&Bs[(size_t)(j * 16 + l16) * SA + ko];
        acc[0][j] = __builtin_amdgcn_mfma_f32_16x16x32_bf16(a0, bfr, acc[0][j], 0, 0, 0);
        acc[1][j] = __builtin_amdgcn_mfma_f32_16x16x32_bf16(a1, bfr, acc[1][j], 0, 0, 0);
      }
    }
    __syncthreads();
    float* Cl = (float*)smem;            // 128 x 132 (2-way = free)
    #pragma unroll
    for (int i = 0; i < 2; i++) {
      int rl0 = w * 32 + i * 16 + quad * 4;
      #pragma unroll
      for (int j = 0; j < 8; j++) {
        int cl = j * 16 + l16;
        float bv = bias[n0 + cl];
        #pragma unroll
        for (int rg = 0; rg < 4; rg++)
          Cl[(rl0 + rg) * 132 + cl] = acc[i][j][rg] + bv;
      }
    }
    __syncthreads();
    for (int task = t; task < 2048; task += 256) {
      int row = task >> 4, seg = task & 15;
      int gr = r0 + row;
      if (gr >= M) continue;
      const float* cp = Cl + row * 132 + seg * 8;
      float4 v0 = *(const float4*)cp;
      float4 v1 = *(const float4*)(cp + 4);
      uint4 o;
      o.x = (unsigned)f2b(v0.x) | ((unsigned)f2b(v0.y) << 16);
      o.y = (unsigned)f2b(v0.z) | ((unsigned)f2b(v0.w) << 16);
      o.z = (unsigned)f2b(v1.x) | ((unsigned)f2b(v1.y) << 16);
      o.w = (unsigned)f2b(v1.z) | ((unsigned)f2b(v1.w) << 16);
      *(uint4*)&C[(size_t)gr * HD + n0 + seg * 8] = o;
    }
  } else {
    f32x4 acc[2][4];
    #pragma unroll
    for (int i = 0; i < 2; i++)
      #pragma unroll
      for (int j = 0; j < 4; j++) acc[i][j] = (f32x4){0.f, 0.f, 0.f, 0.f};
    for (int ks = 0; ks < K; ks += 32) {
      int ko = ks + quad * 8;
      short8 a0 = *(const short8*)&As[(size_t)arow0 * SA + ko];
      short8 a1 = *(const short8*)&As[(size_t)(arow0 + 16) * SA + ko];
      #pragma unroll
      for (int j = 0; j < 4; j++) {
        short8 bfr = *(const short8*)&Bs[(size_t)(j * 16 + l16) * SA + ko];
        acc[0][j] = __builtin_amdgcn_mfma_f32_16x16x32_bf16(a0, bfr, acc[0][j], 0, 0, 0);
        acc[1][j] = __builtin_amdgcn_mfma_f32_16x16x32_bf16(a1, bfr, acc[1][j], 0, 0, 0);
      }
    }
    float* sp[4]; float bav[4];
    #pragma unroll
    for (int j = 0; j < 4; j++) {
      int col = j * 16 + l16;
      int m = col >> 3, h = col & 7;
      float* p = nullptr;
      if (ty < 3) {
        if (m < 3)       p = wsf + ASCC + (size_t)(3*ty + m) * NC * H_;
        else if (m < 6)  p = wsf + ADCC + (size_t)(3*(m-3) + ty) * NC * H_;
        else if (m == 6) p = wsf + ASCS + (size_t)ty * NC * H_;
      } else if (m < 3)  p = wsf + ADCS + (size_t)m * NS * H_;
      sp[j] = p ? (p + h) : nullptr;
      bav[j] = wsf[BAF + ty * 64 + col];
    }
    #pragma unroll
    for (int i = 0; i < 2; i++) {
      int rl0 = w * 32 + i * 16 + quad * 4;
      #pragma unroll
      for (int j = 0; j < 4; j++) {
        if (!sp[j]) continue;
        #pragma unroll
        for (int rg = 0; rg < 4; rg++) {
          int gr = r0 + rl0 + rg;
          // pre-scale by log2(e) so k_agg does exp2 directly (lrelu commutes
          // with a positive scale).
          if (gr < M) sp[j][(size_t)gr * 8] = (acc[i][j][rg] + bav[j]) * 1.44269504089f;
        }
      }
    }
  }
}

// ================= K3: aggregation (R12 latency-MLP rewrite) =================
// 1 wave/dst node. Phase 1: all-relation scores -> unnormalized w in LDS + Z.
// Phase 2: pure message-gather with 8-edge double-buffer prefetched across
// relation boundaries (8-16 coalesced 512B loads in flight per wave).
__device__ __forceinline__ void loadg8(uint2* buf, int srcv, int cl, int g,
                                       const char* wb, int lb) {
  #pragma unroll
  for (int ee = 0; ee < 8; ee++) {
    int sre = __builtin_amdgcn_readlane(srcv, min(g + ee, cl));
    buf[ee] = *(const uint2*)(wb + ((size_t)(unsigned)sre << 9) + lb);
  }
}
__device__ __forceinline__ void consume8(const uint2* buf, const float* wp,
                                         f32x2& sA, f32x2& sB) {
  #pragma unroll
  for (int ee = 0; ee < 8; ee++) {
    float wv = wp[ee * 8];
    f32x2 q0, q1;
    q0.x = bl(buf[ee].x); q0.y = bh(buf[ee].x);
    q1.x = bl(buf[ee].y); q1.y = bh(buf[ee].y);
    sA += q0 * wv;
    sB += q1 * wv;
  }
}

__global__ __launch_bounds__(256) void k_agg(const u16* wsu, const float* wsf,
                                             const int* cnts, const u16* slt,
                                             float* out) {
  __shared__ float Wsm[4 * 1536];                  // 3 rel x 64 edge x 8 head / wave
  int t = threadIdx.x, lane = t & 63, w = t >> 6;
  int node = blockIdx.x * 4 + w;
  int l3 = lane >> 3, h7 = lane & 7;
  int lb = lane * 8;                               // byte offset in 512B msg row
  float* Wv = Wsm + w * 1536;
  bool isC = node < 3 * NC;
  int dtype = 0, n;
  if (isC) { dtype = node / NC; n = node - dtype * NC; } else { n = node - 3 * NC; }

  // ---- hoist all-relation metadata (independent loads back-to-back) ----
  int cidx[3]; const float* ASp[3]; const float* adnp[3]; const char* wb[3];
  #pragma unroll
  for (int j = 0; j < 3; j++) {
    if (isC) {
      int r = j * 3 + dtype;
      cidx[j] = r * NC + n;
      ASp[j]  = wsf + ASCC + (size_t)r * NC * H_;
      adnp[j] = wsf + ADCC + (size_t)r * NC * H_ + (size_t)n * H_ + h7;
      wb[j]   = (const char*)(wsu + WHB_CC + (size_t)r * NC * HD);
    } else {
      cidx[j] = 90000 + j * NS + n;
      ASp[j]  = wsf + ASCS + (size_t)j * NC * H_;
      adnp[j] = wsf + ADCS + (size_t)j * NS * H_ + (size_t)n * H_ + h7;
      wb[j]   = (const char*)(wsu + WHB_CS + (size_t)j * NC * HD);
    }
  }
  int cnt[3], clm[3], srcv[3]; float adn[3];
  #pragma unroll
  for (int j = 0; j < 3; j++) cnt[j] = min(cnts[cidx[j]], CAP);
  #pragma unroll
  for (int j = 0; j < 3; j++) {
    clm[j] = max(cnt[j] - 1, 0);
    srcv[j] = (int)slt[(size_t)cidx[j] * CAP + min(lane, clm[j])];
  }
  #pragma unroll
  for (int j = 0; j < 3; j++) adn[j] = *adnp[j];

  // ---- issue first payload group now; latency hides under phase 1 ----
  uint2 cur[8], nxt[8];
  loadg8(cur, srcv[0], clm[0], 0, wb[0], lb);

  // ---- phase 1: scores for all relations -> LDS (unnormalized) + 1/Z ----
  float invp[3];
  #pragma unroll
  for (int j = 0; j < 3; j++) {
    float zac = 0.f;
    int c = cnt[j];
    for (int g = 0; g < c; g += 8) {
      int e = g + l3;
      int sid = __shfl(srcv[j], min(e, clm[j]));
      float sc = ASp[j][(size_t)sid * H_ + h7] + adn[j];
      sc = fmaxf(sc, ALPHA * sc);
      float wv = (e < c) ? __builtin_amdgcn_exp2f(sc) : 0.f;
      zac += wv;
      Wv[j * 512 + g * 8 + lane] = wv;             // contiguous per wave
    }
    zac += __shfl_xor(zac, 8);
    zac += __shfl_xor(zac, 16);
    zac += __shfl_xor(zac, 32);
    float inv = 1.f / zac;                         // Z[h] in every lane (by h7)
    invp[j] = (c > 0) ? __shfl(inv, l3) : 0.f;     // broadcast to payload h=l3
  }

  // ---- phase 2: gather loop, double-buffered across relation boundaries ----
  f32x2 tA = {0.f, 0.f}, tB = {0.f, 0.f};
#define RELBODY(J, JN, LAST)                                                 \
  {                                                                          \
    int c = cnt[J];                                                          \
    if (c > 0) {                                                             \
      f32x2 sA = {0.f, 0.f}, sB = {0.f, 0.f};                                \
      for (int g = 0; g < c; g += 8) {                                       \
        if (g + 8 < c) loadg8(nxt, srcv[J], clm[J], g + 8, wb[J], lb);       \
        else if (!(LAST)) loadg8(nxt, srcv[JN], clm[JN], 0, wb[JN], lb);     \
        consume8(cur, Wv + (J) * 512 + g * 8 + l3, sA, sB);                  \
        _Pragma("unroll")                                                    \
        for (int ee = 0; ee < 8; ee++) cur[ee] = nxt[ee];                    \
      }                                                                      \
      tA += sA * invp[J];                                                    \
      tB += sB * invp[J];                                                    \
    } else if (!(LAST)) {                                                    \
      loadg8(cur, srcv[JN], clm[JN], 0, wb[JN], lb);                         \
    }                                                                        \
  }
  RELBODY(0, 1, false)
  RELBODY(1, 2, false)
  RELBODY(2, 2, true)
#undef RELBODY

  if (!isC) {                                      // state self term
    uint2 m = *(const uint2*)((const char*)(wsu + WHB_IN) + (size_t)n * 512 + lb);
    tA.x += bl(m.x); tA.y += bh(m.x);
    tB.x += bl(m.y); tB.y += bh(m.y);
  }
  float4 v = make_float4(fmaxf(tA.x, 0.f), fmaxf(tA.y, 0.f),
                         fmaxf(tB.x, 0.f), fmaxf(tB.y, 0.f));
  *(float4*)(out + (size_t)node * HD + lane * 4) = v;
}

extern "C" void kernel_launch(void* const* d_in, const int* in_sizes, int n_in,
                              void* d_out, int out_size, void* d_ws, size_t ws_size,
                              hipStream_t stream) {
  (void)in_sizes; (void)n_in; (void)out_size; (void)ws_size;
  const float* f1    = (const float*)d_in[0];
  const float* f2    = (const float*)d_in[1];
  const float* f3    = (const float*)d_in[2];
  const float* fs    = (const float*)d_in[3];
  const float* Wnode = (const float*)d_in[4];
  const float* bnode = (const float*)d_in[5];
  const float* Wcc   = (const float*)d_in[6];
  const float* bcc   = (const float*)d_in[7];
  const float* Wcs   = (const float*)d_in[8];
  const float* bcs   = (const float*)d_in[9];
  const float* Win   = (const float*)d_in[10];
  const float* bin   = (const float*)d_in[11];
  const float* accv  = (const float*)d_in[12];
  const float* acsv  = (const float*)d_in[13];
  const int* eccs    = (const int*)d_in[14];
  const int* eccd    = (const int*)d_in[15];
  const int* ecss    = (const int*)d_in[16];
  const int* ecsd    = (const int*)d_in[17];
  float* wsf = (float*)d_ws;
  u16*   wsu = (u16*)d_ws;
  int*   cnts = (int*)((char*)d_ws + IBYTE);
  u16*   slt  = (u16*)((char*)d_ws + SBYTE);
  float* out = (float*)d_out;

  k_prep<<<dim3(NB_Z0 + NB_FT + NB_WT + NB_FO), 256, 0, stream>>>(
      f1, f2, f3, fs, Wcc, Wcs, Win, Wnode, bcc, bnode, bcs, bin, accv, acsv,
      wsu, wsf, cnts);
  k_fuse<<<dim3(NB_K2), 256, 0, stream>>>(
      wsu, wsf, bcc, bcs, bin, eccs, eccd, ecss, ecsd, cnts, slt);
  k_agg<<<dim3((3 * NC + NS) / 4), 256, 0, stream>>>(wsu, wsf, cnts, slt, out);
}

// Round 3
// 261.605 us; speedup vs baseline: 1.0147x; 1.0147x over previous
//
#include <hip/hip_runtime.h>

// HeteroGAT on MI355X. R13:
//   K1 k_prep: unchanged
//   K2 k_fuse: unchanged (GEMM 4:1 scatter interleave, log2e-prescaled scores)
//   K3 k_agg:  R12's double-buffered cross-relation message pipeline, but with
//              ZERO LDS (R12's 24KB stash halved occupancy -> regression).
//              Scores via R11's in-register wcur prefetch chain; per-relation
//              Z reduce; metadata for all 3 relations hoisted with unclamped
//              slot loads (clamp at use) for fully parallel issue.

#define H_ 8
#define D_ 32
#define HD 256
#define NC 10000
#define NS 1024
#define INC 128
#define INS 64
#define ECC 120000
#define ECS 10000
#define ALPHA 0.2f
#define CAP 64

typedef unsigned short u16;
typedef __attribute__((ext_vector_type(8))) short short8;
typedef __attribute__((ext_vector_type(4))) float f32x4;
typedef __attribute__((ext_vector_type(2))) float f32x2;

// ---- ws layout ----
// u16 region (u16 units)
static constexpr size_t WHB_CC = 0;              // 9*NC*HD
static constexpr size_t WHB_CS = 23040000;       // 3*NC*HD
static constexpr size_t WHB_IN = 30720000;       // NS*HD -> end 30982144 u16
// f32 scores (float units)
static constexpr size_t FB0  = 15491072;
static constexpr size_t ASCC = FB0;              // 9*NC*8
static constexpr size_t ADCC = FB0 + 720000;     // 9*NC*8
static constexpr size_t ASCS = FB0 + 1440000;    // 3*NC*8
static constexpr size_t ADCS = FB0 + 1680000;    // 3*NS*8 -> FB0+1704576
static constexpr size_t BAF  = FB0 + 1704576;    // 4*64 folded bias dots
// bf16 feats + transposed weights (u16 units)
static constexpr size_t FBC  = 34437760;         // 3*NC*128
static constexpr size_t FBS  = 38277760;         // NS*64
static constexpr size_t WTCC = 38343296;         // 9*32768
static constexpr size_t WTCS = 38638208;         // 3*32768
static constexpr size_t WTIN = 38736512;         // 256*64
static constexpr size_t WAT  = 38752896;         // 4*8192 folded attn mats [col][k]
// int counters (byte offset): 93072 ints = 9*NC (cc) then 3*NS (cs)
static constexpr size_t IBYTE = 77768704;
// u16 slots (byte offset): slot for counter c is slt[c*CAP + p]
static constexpr size_t SBYTE = 78140992;

static constexpr int TOTE  = 9 * ECC + 3 * ECS;  // 1,110,000
static constexpr int NB_Z0 = 91;                 // zero: 93072 ints / (int4*256)
static constexpr int NB_FT = 3814;               // feat cvt
static constexpr int NB_WT = 104;                // weight transpose: 13 mats x 8
static constexpr int NB_FO = 32;                 // attn fold: 4 tiles x 8 col-groups
static constexpr int NB_K2 = 2710;               // 542 scatter (g%5==4) + 2168 gemm slots (2157 used)

__device__ __forceinline__ u16 f2b(float f) {
  unsigned u = __float_as_uint(f);
  return (u16)((u + 0x7FFFu + ((u >> 16) & 1u)) >> 16);
}
__device__ __forceinline__ float bl(unsigned u) { return __uint_as_float(u << 16); }
__device__ __forceinline__ float bh(unsigned u) { return __uint_as_float(u & 0xffff0000u); }

// ================= K1: zero + cvt_feat + cvt_w + fold(32) =================
__global__ __launch_bounds__(256) void k_prep(
    const float* f1, const float* f2, const float* f3, const float* fs,
    const float* Wcc, const float* Wcs, const float* Win, const float* Wnode,
    const float* bcc, const float* bnode, const float* bcs, const float* bin,
    const float* accv, const float* acsv,
    u16* wsu, float* wsf, int* cnts) {
  __shared__ float Ls[64 * 65];
  int b = blockIdx.x, t = threadIdx.x;
  if (b < NB_Z0) {                                 // ---- zero counters ----
    int i = b * 256 + t;
    if (i < 23268) ((int4*)cnts)[i] = make_int4(0, 0, 0, 0);
    return;
  }
  b -= NB_Z0;
  if (b < NB_FT) {                                 // ---- f32 -> bf16 feats ----
    const float* src; u16* dst; int idx, n4;
    if (b < 3750) {
      int ty = b / 1250;
      src = (ty == 0) ? f1 : (ty == 1) ? f2 : f3;
      dst = wsu + FBC + (size_t)ty * 1280000;
      idx = (b - ty * 1250) * 256 + t; n4 = 320000;
    } else {
      src = fs; dst = wsu + FBS; idx = (b - 3750) * 256 + t; n4 = 16384;
    }
    if (idx < n4) {
      float4 v = ((const float4*)src)[idx];
      uint2 o;
      o.x = (unsigned)f2b(v.x) | ((unsigned)f2b(v.y) << 16);
      o.y = (unsigned)f2b(v.z) | ((unsigned)f2b(v.w) << 16);
      *(uint2*)(dst + (size_t)idx * 4) = o;
    }
    return;
  }
  b -= NB_FT;
  if (b < NB_WT) {                                 // ---- weight transpose, LDS tile ----
    int mat = b >> 3, sub = b & 7;                 // mat 0..12
    int K = (mat == 12) ? INS : INC;
    if (mat == 12 && sub >= 4) return;
    int k0 = (sub >> 2) * 64, n0 = (sub & 3) * 64;
    const float* src; u16* dst;
    if (mat < 9)        { src = Wcc + (size_t)mat * INC * HD;        dst = wsu + WTCC + (size_t)mat * 32768; }
    else if (mat < 12)  { src = Wcs + (size_t)(mat - 9) * INC * HD;  dst = wsu + WTCS + (size_t)(mat - 9) * 32768; }
    else                { src = Win;                                 dst = wsu + WTIN; }
    #pragma unroll
    for (int it = 0; it < 4; it++) {
      int idx = t + it * 256;
      int r = idx >> 4, c4 = idx & 15;
      float4 v = *(const float4*)&src[(size_t)(k0 + r) * HD + n0 + c4 * 4];
      Ls[r * 65 + c4 * 4 + 0] = v.x; Ls[r * 65 + c4 * 4 + 1] = v.y;
      Ls[r * 65 + c4 * 4 + 2] = v.z; Ls[r * 65 + c4 * 4 + 3] = v.w;
    }
    __syncthreads();
    int n = t >> 2, k8 = (t & 3) * 16;
    unsigned o[8];
    #pragma unroll
    for (int j = 0; j < 8; j++) {
      u16 lo = f2b(Ls[(k8 + 2 * j) * 65 + n]);
      u16 hi = f2b(Ls[(k8 + 2 * j + 1) * 65 + n]);
      o[j] = (unsigned)lo | ((unsigned)hi << 16);
    }
    uint4* dp = (uint4*)&dst[(size_t)(n0 + n) * K + k0 + k8];
    dp[0] = make_uint4(o[0], o[1], o[2], o[3]);
    dp[1] = make_uint4(o[4], o[5], o[6], o[7]);
    return;
  }
  b -= NB_WT;                                      // ---- attn fold: 4 tiles x 8 groups ----
  int tile = b >> 3, sub = b & 7;
  int K = (tile == 3) ? INS : INC;
  int c0 = sub * 8;
  for (int idx = t; idx < 8 * K; idx += 256) {
    int col = c0 + idx / K, k = idx % K;
    int m = col >> 3, h = col & 7;
    const float* W = nullptr; const float* av = nullptr;
    if (tile < 3) {
      if (m < 3)      { int r = 3*tile + m; W = Wcc + (size_t)r*INC*HD;   av = accv + (size_t)r*512 + h*32; }
      else if (m < 6) { int r = 3*(m-3) + tile; W = Wnode + (size_t)tile*INC*HD; av = accv + (size_t)r*512 + 256 + h*32; }
      else if (m == 6){ W = Wcs + (size_t)tile*INC*HD; av = acsv + (size_t)tile*512 + h*32; }
    } else if (m < 3) { W = Win; av = acsv + (size_t)m*512 + 256 + h*32; }
    float s = 0.f;
    if (W) {
      const float* wp = W + (size_t)k * HD + h * 32;
      #pragma unroll 8
      for (int d = 0; d < 32; d++) s += wp[d] * av[d];
    }
    wsu[WAT + (size_t)tile * 8192 + (size_t)col * K + k] = f2b(s);
  }
  if (sub == 0 && t < 64) {
    int col = t, m = col >> 3, h = col & 7;
    const float* bb = nullptr; const float* av = nullptr;
    if (tile < 3) {
      if (m < 3)      { int r = 3*tile + m; bb = bcc + (size_t)r*HD;  av = accv + (size_t)r*512 + h*32; }
      else if (m < 6) { int r = 3*(m-3) + tile; bb = bnode + (size_t)tile*HD; av = accv + (size_t)r*512 + 256 + h*32; }
      else if (m == 6){ bb = bcs + (size_t)tile*HD; av = acsv + (size_t)tile*512 + h*32; }
    } else if (m < 3) { bb = bin; av = acsv + (size_t)m*512 + 256 + h*32; }
    float s = 0.f;
    if (bb) for (int d = 0; d < 32; d++) s += bb[h*32 + d] * av[d];
    wsf[BAF + tile * 64 + col] = s;
  }
}

// ================= K2: interleaved scatter (1 of 5) + GEMMs =================
__global__ __launch_bounds__(256, 2) void k_fuse(
    u16* wsu, float* wsf, const float* bcc, const float* bcs, const float* bin,
    const int* eccs, const int* eccd, const int* ecss, const int* ecsd,
    int* cnts, u16* slt) {
  __shared__ __align__(16) char smem[69632];
  int gb = blockIdx.x, t = threadIdx.x;
  if ((gb % 5) == 4) {                             // ---- edge scatter, 8/thread ----
    int k = gb / 5;                                // 0..541
    int i0 = (k * 256 + t) * 8;
    if (i0 >= TOTE) return;
    int dd[8], ss[8], p[8];
    int cbase;
    if (i0 < 9 * ECC) {
      int r = i0 / ECC;
      int4 d0 = *(const int4*)&eccd[i0]; int4 d1 = *(const int4*)&eccd[i0 + 4];
      int4 s0 = *(const int4*)&eccs[i0]; int4 s1 = *(const int4*)&eccs[i0 + 4];
      dd[0]=d0.x; dd[1]=d0.y; dd[2]=d0.z; dd[3]=d0.w;
      dd[4]=d1.x; dd[5]=d1.y; dd[6]=d1.z; dd[7]=d1.w;
      ss[0]=s0.x; ss[1]=s0.y; ss[2]=s0.z; ss[3]=s0.w;
      ss[4]=s1.x; ss[5]=s1.y; ss[6]=s1.z; ss[7]=s1.w;
      cbase = r * NC;
    } else {
      int u0 = i0 - 9 * ECC;
      int r = u0 / ECS;
      int4 d0 = *(const int4*)&ecsd[u0]; int4 d1 = *(const int4*)&ecsd[u0 + 4];
      int4 s0 = *(const int4*)&ecss[u0]; int4 s1 = *(const int4*)&ecss[u0 + 4];
      dd[0]=d0.x; dd[1]=d0.y; dd[2]=d0.z; dd[3]=d0.w;
      dd[4]=d1.x; dd[5]=d1.y; dd[6]=d1.z; dd[7]=d1.w;
      ss[0]=s0.x; ss[1]=s0.y; ss[2]=s0.z; ss[3]=s0.w;
      ss[4]=s1.x; ss[5]=s1.y; ss[6]=s1.z; ss[7]=s1.w;
      cbase = 90000 + r * NS;
    }
    #pragma unroll
    for (int q = 0; q < 8; q++) p[q] = atomicAdd(&cnts[cbase + dd[q]], 1);
    #pragma unroll
    for (int q = 0; q < 8; q++)
      if (p[q] < CAP) slt[((size_t)(cbase + dd[q])) * CAP + p[q]] = (u16)ss[q];
    return;
  }
  int g = 4 * (gb / 5) + (gb % 5);                 // gemm id 0..2167
  if (g >= 2157) return;
  u16* As = (u16*)smem;
  u16* Bs = (u16*)(smem + 34816);
  const u16 *A, *Bt; const float* bias = nullptr; u16* C = nullptr;
  int M, K, r0, n0 = 0, ty = 0;
  bool isScore = false;
  if (g < 1896) {
    int z = g / 158, rem = g - z * 158;
    int by = rem / 79, bx = rem - by * 79;
    r0 = bx * 128; n0 = by * 128; M = NC; K = 128;
    if (z < 9) { A = wsu + FBC + (size_t)(z/3)*1280000; Bt = wsu + WTCC + (size_t)z*32768; bias = bcc + (size_t)z*HD; C = wsu + WHB_CC + (size_t)z*NC*HD; }
    else { int q = z - 9; A = wsu + FBC + (size_t)q*1280000; Bt = wsu + WTCS + (size_t)q*32768; bias = bcs + (size_t)q*HD; C = wsu + WHB_CS + (size_t)q*NC*HD; }
  } else if (g < 1912) {
    int loc = g - 1896; int by = loc / 8, bx = loc - by * 8;
    r0 = bx * 128; n0 = by * 128; M = NS; K = 64;
    A = wsu + FBS; Bt = wsu + WTIN; bias = bin; C = wsu + WHB_IN;
  } else if (g < 2149) {
    isScore = true; ty = (g - 1912) / 79; int bx = (g - 1912) % 79;
    r0 = bx * 128; M = NC; K = 128;
    A = wsu + FBC + (size_t)ty * 1280000; Bt = wsu + WAT + (size_t)ty * 8192;
  } else {
    isScore = true; ty = 3; int bx = g - 2149;
    r0 = bx * 128; M = NS; K = 64;
    A = wsu + FBS; Bt = wsu + WAT + (size_t)3 * 8192;
  }
  int SA = K + 8;
  int NB = isScore ? 64 : 128;
  {
    int ksh = (K == 128) ? 4 : 3;
    int kmask = (1 << ksh) - 1;
    int sc8 = SA >> 3;
    const uint4* ga = (const uint4*)(A + (size_t)r0 * K);
    const uint4* gb2 = (const uint4*)(Bt + (size_t)n0 * K);
    uint4* la = (uint4*)As; uint4* lb = (uint4*)Bs;
    int tota = (128 * K) >> 3, totb = (NB * K) >> 3;
    for (int i = t; i < tota; i += 256) la[(i >> ksh) * sc8 + (i & kmask)] = ga[i];
    for (int i = t; i < totb; i += 256) lb[(i >> ksh) * sc8 + (i & kmask)] = gb2[i];
  }
  __syncthreads();
  int lane = t & 63, w = t >> 6, l16 = lane & 15, quad = lane >> 4;
  int arow0 = w * 32 + l16;
  if (!isScore) {
    f32x4 acc[2][8];
    #pragma unroll
    for (int i = 0; i < 2; i++)
      #pragma unroll
      for (int j = 0; j < 8; j++) acc[i][j] = (f32x4){0.f, 0.f, 0.f, 0.f};
    for (int ks = 0; ks < K; ks += 32) {
      int ko = ks + quad * 8;
      short8 a0 = *(const short8*)&As[(size_t)arow0 * SA + ko];
      short8 a1 = *(const short8*)&As[(size_t)(arow0 + 16) * SA + ko];
      #pragma unroll
      for (int j = 0; j < 8; j++) {
        short8 bfr = *(const short8*)&Bs[(size_t)(j * 16 + l16) * SA + ko];
        acc[0][j] = __builtin_amdgcn_mfma_f32_16x16x32_bf16(a0, bfr, acc[0][j], 0, 0, 0);
        acc[1][j] = __builtin_amdgcn_mfma_f32_16x16x32_bf16(a1, bfr, acc[1][j], 0, 0, 0);
      }
    }
    __syncthreads();
    float* Cl = (float*)smem;            // 128 x 132 (2-way = free)
    #pragma unroll
    for (int i = 0; i < 2; i++) {
      int rl0 = w * 32 + i * 16 + quad * 4;
      #pragma unroll
      for (int j = 0; j < 8; j++) {
        int cl = j * 16 + l16;
        float bv = bias[n0 + cl];
        #pragma unroll
        for (int rg = 0; rg < 4; rg++)
          Cl[(rl0 + rg) * 132 + cl] = acc[i][j][rg] + bv;
      }
    }
    __syncthreads();
    for (int task = t; task < 2048; task += 256) {
      int row = task >> 4, seg = task & 15;
      int gr = r0 + row;
      if (gr >= M) continue;
      const float* cp = Cl + row * 132 + seg * 8;
      float4 v0 = *(const float4*)cp;
      float4 v1 = *(const float4*)(cp + 4);
      uint4 o;
      o.x = (unsigned)f2b(v0.x) | ((unsigned)f2b(v0.y) << 16);
      o.y = (unsigned)f2b(v0.z) | ((unsigned)f2b(v0.w) << 16);
      o.z = (unsigned)f2b(v1.x) | ((unsigned)f2b(v1.y) << 16);
      o.w = (unsigned)f2b(v1.z) | ((unsigned)f2b(v1.w) << 16);
      *(uint4*)&C[(size_t)gr * HD + n0 + seg * 8] = o;
    }
  } else {
    f32x4 acc[2][4];
    #pragma unroll
    for (int i = 0; i < 2; i++)
      #pragma unroll
      for (int j = 0; j < 4; j++) acc[i][j] = (f32x4){0.f, 0.f, 0.f, 0.f};
    for (int ks = 0; ks < K; ks += 32) {
      int ko = ks + quad * 8;
      short8 a0 = *(const short8*)&As[(size_t)arow0 * SA + ko];
      short8 a1 = *(const short8*)&As[(size_t)(arow0 + 16) * SA + ko];
      #pragma unroll
      for (int j = 0; j < 4; j++) {
        short8 bfr = *(const short8*)&Bs[(size_t)(j * 16 + l16) * SA + ko];
        acc[0][j] = __builtin_amdgcn_mfma_f32_16x16x32_bf16(a0, bfr, acc[0][j], 0, 0, 0);
        acc[1][j] = __builtin_amdgcn_mfma_f32_16x16x32_bf16(a1, bfr, acc[1][j], 0, 0, 0);
      }
    }
    float* sp[4]; float bav[4];
    #pragma unroll
    for (int j = 0; j < 4; j++) {
      int col = j * 16 + l16;
      int m = col >> 3, h = col & 7;
      float* p = nullptr;
      if (ty < 3) {
        if (m < 3)       p = wsf + ASCC + (size_t)(3*ty + m) * NC * H_;
        else if (m < 6)  p = wsf + ADCC + (size_t)(3*(m-3) + ty) * NC * H_;
        else if (m == 6) p = wsf + ASCS + (size_t)ty * NC * H_;
      } else if (m < 3)  p = wsf + ADCS + (size_t)m * NS * H_;
      sp[j] = p ? (p + h) : nullptr;
      bav[j] = wsf[BAF + ty * 64 + col];
    }
    #pragma unroll
    for (int i = 0; i < 2; i++) {
      int rl0 = w * 32 + i * 16 + quad * 4;
      #pragma unroll
      for (int j = 0; j < 4; j++) {
        if (!sp[j]) continue;
        #pragma unroll
        for (int rg = 0; rg < 4; rg++) {
          int gr = r0 + rl0 + rg;
          // pre-scale by log2(e) so k_agg does exp2 directly (lrelu commutes
          // with a positive scale).
          if (gr < M) sp[j][(size_t)gr * 8] = (acc[i][j][rg] + bav[j]) * 1.44269504089f;
        }
      }
    }
  }
}

// ================= K3: aggregation (R13: DB pipeline, zero LDS) =================
__device__ __forceinline__ void loadg8(uint2* buf, const char* wb, int srcv,
                                       int cl, int g, int lb) {
  #pragma unroll
  for (int ee = 0; ee < 8; ee++) {
    int sre = __builtin_amdgcn_readlane(srcv, min(g + ee, cl));
    buf[ee] = *(const uint2*)(wb + ((size_t)(unsigned)sre << 9) + lb);
  }
}
__device__ __forceinline__ void consume8(const uint2* buf, float wold, int l3,
                                         f32x2& sA, f32x2& sB) {
  #pragma unroll
  for (int ee = 0; ee < 8; ee++) {
    float wv = __shfl(wold, ee * 8 + l3);
    f32x2 q0, q1;
    q0.x = bl(buf[ee].x); q0.y = bh(buf[ee].x);
    q1.x = bl(buf[ee].y); q1.y = bh(buf[ee].y);
    sA += q0 * wv;
    sB += q1 * wv;
  }
}
// scores for 8 edges starting at g; lane = (e_loc<<3)|h layout
__device__ __forceinline__ float score8(const float* ASp, float adn, int srcv,
                                        int cl, int c, int g, int l3, int h7) {
  int e = g + l3;
  int sid = __shfl(srcv, min(e, cl));
  float sc = ASp[(size_t)sid * H_ + h7] + adn;
  sc = fmaxf(sc, ALPHA * sc);
  return (e < c) ? __builtin_amdgcn_exp2f(sc) : 0.f;
}

__global__ __launch_bounds__(256) void k_agg(const u16* wsu, const float* wsf,
                                             const int* cnts, const u16* slt,
                                             float* out) {
  int t = threadIdx.x, lane = t & 63, w = t >> 6;
  int node = blockIdx.x * 4 + w;
  int l3 = lane >> 3, h7 = lane & 7;
  int lb = lane * 8;                               // byte offset in 512B msg row
  bool isC = node < 3 * NC;
  int dtype = 0, n;
  if (isC) { dtype = node / NC; n = node - dtype * NC; } else { n = node - 3 * NC; }

  // ---- hoisted metadata for all 3 relations (parallel issue) ----
  int cidx[3]; const float* ASp[3]; const float* adnp[3]; const char* wb[3];
  #pragma unroll
  for (int j = 0; j < 3; j++) {
    if (isC) {
      int r = j * 3 + dtype;
      cidx[j] = r * NC + n;
      ASp[j]  = wsf + ASCC + (size_t)r * NC * H_;
      adnp[j] = wsf + ADCC + (size_t)r * NC * H_ + (size_t)n * H_ + h7;
      wb[j]   = (const char*)(wsu + WHB_CC + (size_t)r * NC * HD);
    } else {
      cidx[j] = 90000 + j * NS + n;
      ASp[j]  = wsf + ASCS + (size_t)j * NC * H_;
      adnp[j] = wsf + ADCS + (size_t)j * NS * H_ + (size_t)n * H_ + h7;
      wb[j]   = (const char*)(wsu + WHB_CS + (size_t)j * NC * HD);
    }
  }
  int srcv[3]; float adn[3]; int cnt[3], clm[3];
  // slots loaded UNCLAMPED (independent of cnts) -> all loads issue in parallel;
  // clamped only at use. Garbage rows stay inside ws and are weight-masked.
  #pragma unroll
  for (int j = 0; j < 3; j++) srcv[j] = (int)slt[(size_t)cidx[j] * CAP + lane];
  #pragma unroll
  for (int j = 0; j < 3; j++) adn[j] = *adnp[j];
  #pragma unroll
  for (int j = 0; j < 3; j++) cnt[j] = min(cnts[cidx[j]], CAP);
  #pragma unroll
  for (int j = 0; j < 3; j++) clm[j] = max(cnt[j] - 1, 0);

  // ---- prime pipeline: rel0 group0 messages + scores ----
  uint2 cur[8], nxt[8];
  loadg8(cur, wb[0], srcv[0], clm[0], 0, lb);
  float wcur = score8(ASp[0], adn[0], srcv[0], clm[0], cnt[0], 0, l3, h7);

  f32x2 tA = {0.f, 0.f}, tB = {0.f, 0.f};
#define RELBODY(J, JN, LAST)                                                  \
  {                                                                           \
    int c = cnt[J];                                                           \
    if (c > 0) {                                                              \
      f32x2 sA = {0.f, 0.f}, sB = {0.f, 0.f};                                 \
      float zac = 0.f;                                                        \
      for (int g = 0; g < c; g += 8) {                                        \
        if (g + 8 < c)                                                        \
          loadg8(nxt, wb[J], srcv[J], clm[J], g + 8, lb);                     \
        else if (!(LAST))                                                     \
          loadg8(nxt, wb[JN], srcv[JN], clm[JN], 0, lb);                      \
        float wold = wcur;                                                    \
        zac += wold;                                                          \
        if (g + 8 < c)                                                        \
          wcur = score8(ASp[J], adn[J], srcv[J], clm[J], c, g + 8, l3, h7);   \
        consume8(cur, wold, l3, sA, sB);                                      \
        _Pragma("unroll")                                                     \
        for (int ee = 0; ee < 8; ee++) cur[ee] = nxt[ee];                     \
      }                                                                       \
      zac += __shfl_xor(zac, 8);                                              \
      zac += __shfl_xor(zac, 16);                                             \
      zac += __shfl_xor(zac, 32);                                             \
      float inv = 1.f / zac;                                                  \
      float invp = __shfl(inv, l3);                                           \
      tA += sA * invp;                                                        \
      tB += sB * invp;                                                        \
      if (!(LAST) && cnt[JN] > 0)                                             \
        wcur = score8(ASp[JN], adn[JN], srcv[JN], clm[JN], cnt[JN], 0, l3, h7); \
    } else if (!(LAST)) {                                                     \
      loadg8(cur, wb[JN], srcv[JN], clm[JN], 0, lb);                          \
      if (cnt[JN] > 0)                                                        \
        wcur = score8(ASp[JN], adn[JN], srcv[JN], clm[JN], cnt[JN], 0, l3, h7); \
    }                                                                         \
  }
  RELBODY(0, 1, false)
  RELBODY(1, 2, false)
  RELBODY(2, 2, true)
#undef RELBODY

  if (!isC) {                                      // state self term
    uint2 m = *(const uint2*)((const char*)(wsu + WHB_IN) + (size_t)n * 512 + lb);
    tA.x += bl(m.x); tA.y += bh(m.x);
    tB.x += bl(m.y); tB.y += bh(m.y);
  }
  float4 v = make_float4(fmaxf(tA.x, 0.f), fmaxf(tA.y, 0.f),
                         fmaxf(tB.x, 0.f), fmaxf(tB.y, 0.f));
  *(float4*)(out + (size_t)node * HD + lane * 4) = v;
}

extern "C" void kernel_launch(void* const* d_in, const int* in_sizes, int n_in,
                              void* d_out, int out_size, void* d_ws, size_t ws_size,
                              hipStream_t stream) {
  (void)in_sizes; (void)n_in; (void)out_size; (void)ws_size;
  const float* f1    = (const float*)d_in[0];
  const float* f2    = (const float*)d_in[1];
  const float* f3    = (const float*)d_in[2];
  const float* fs    = (const float*)d_in[3];
  const float* Wnode = (const float*)d_in[4];
  const float* bnode = (const float*)d_in[5];
  const float* Wcc   = (const float*)d_in[6];
  const float* bcc   = (const float*)d_in[7];
  const float* Wcs   = (const float*)d_in[8];
  const float* bcs   = (const float*)d_in[9];
  const float* Win   = (const float*)d_in[10];
  const float* bin   = (const float*)d_in[11];
  const float* accv  = (const float*)d_in[12];
  const float* acsv  = (const float*)d_in[13];
  const int* eccs    = (const int*)d_in[14];
  const int* eccd    = (const int*)d_in[15];
  const int* ecss    = (const int*)d_in[16];
  const int* ecsd    = (const int*)d_in[17];
  float* wsf = (float*)d_ws;
  u16*   wsu = (u16*)d_ws;
  int*   cnts = (int*)((char*)d_ws + IBYTE);
  u16*   slt  = (u16*)((char*)d_ws + SBYTE);
  float* out = (float*)d_out;

  k_prep<<<dim3(NB_Z0 + NB_FT + NB_WT + NB_FO), 256, 0, stream>>>(
      f1, f2, f3, fs, Wcc, Wcs, Win, Wnode, bcc, bnode, bcs, bin, accv, acsv,
      wsu, wsf, cnts);
  k_fuse<<<dim3(NB_K2), 256, 0, stream>>>(
      wsu, wsf, bcc, bcs, bin, eccs, eccd, ecss, ecsd, cnts, slt);
  k_agg<<<dim3((3 * NC + NS) / 4), 256, 0, stream>>>(wsu, wsf, cnts, slt, out);
}

// Round 4
// 250.732 us; speedup vs baseline: 1.0587x; 1.0434x over previous
//
#include <hip/hip_runtime.h>

// HeteroGAT on MI355X. R14:
//   K1 k_prep: unchanged
//   K2 k_fuse: unchanged (GEMM 4:1 scatter interleave, log2e-prescaled scores)
//   K3 k_agg:  R11 structure (VGPR 32, occ 70%, 80us) + XCD-chunked bijective
//              block swizzle (m204): each XCD gets a contiguous node range so
//              its L2 only holds the 3-4 relation message pools of its dtype
//              (~15-18MB, 4.6x row reuse) instead of all 12 pools (62MB).
//              Theory: k_agg is L2-miss-bandwidth bound (dur ~= FETCH/3.4TB/s
//              + 11us across R0/R11/R12/R13); cut FETCH, cut time.

#define H_ 8
#define D_ 32
#define HD 256
#define NC 10000
#define NS 1024
#define INC 128
#define INS 64
#define ECC 120000
#define ECS 10000
#define ALPHA 0.2f
#define CAP 64

typedef unsigned short u16;
typedef __attribute__((ext_vector_type(8))) short short8;
typedef __attribute__((ext_vector_type(4))) float f32x4;
typedef __attribute__((ext_vector_type(2))) float f32x2;

// ---- ws layout ----
// u16 region (u16 units)
static constexpr size_t WHB_CC = 0;              // 9*NC*HD
static constexpr size_t WHB_CS = 23040000;       // 3*NC*HD
static constexpr size_t WHB_IN = 30720000;       // NS*HD -> end 30982144 u16
// f32 scores (float units)
static constexpr size_t FB0  = 15491072;
static constexpr size_t ASCC = FB0;              // 9*NC*8
static constexpr size_t ADCC = FB0 + 720000;     // 9*NC*8
static constexpr size_t ASCS = FB0 + 1440000;    // 3*NC*8
static constexpr size_t ADCS = FB0 + 1680000;    // 3*NS*8 -> FB0+1704576
static constexpr size_t BAF  = FB0 + 1704576;    // 4*64 folded bias dots
// bf16 feats + transposed weights (u16 units)
static constexpr size_t FBC  = 34437760;         // 3*NC*128
static constexpr size_t FBS  = 38277760;         // NS*64
static constexpr size_t WTCC = 38343296;         // 9*32768
static constexpr size_t WTCS = 38638208;         // 3*32768
static constexpr size_t WTIN = 38736512;         // 256*64
static constexpr size_t WAT  = 38752896;         // 4*8192 folded attn mats [col][k]
// int counters (byte offset): 93072 ints = 9*NC (cc) then 3*NS (cs)
static constexpr size_t IBYTE = 77768704;
// u16 slots (byte offset): slot for counter c is slt[c*CAP + p]
static constexpr size_t SBYTE = 78140992;

static constexpr int TOTE  = 9 * ECC + 3 * ECS;  // 1,110,000
static constexpr int NB_Z0 = 91;                 // zero: 93072 ints / (int4*256)
static constexpr int NB_FT = 3814;               // feat cvt
static constexpr int NB_WT = 104;                // weight transpose: 13 mats x 8
static constexpr int NB_FO = 32;                 // attn fold: 4 tiles x 8 col-groups
static constexpr int NB_K2 = 2710;               // 542 scatter (g%5==4) + 2168 gemm slots (2157 used)

__device__ __forceinline__ u16 f2b(float f) {
  unsigned u = __float_as_uint(f);
  return (u16)((u + 0x7FFFu + ((u >> 16) & 1u)) >> 16);
}
__device__ __forceinline__ float bl(unsigned u) { return __uint_as_float(u << 16); }
__device__ __forceinline__ float bh(unsigned u) { return __uint_as_float(u & 0xffff0000u); }

// ================= K1: zero + cvt_feat + cvt_w + fold(32) =================
__global__ __launch_bounds__(256) void k_prep(
    const float* f1, const float* f2, const float* f3, const float* fs,
    const float* Wcc, const float* Wcs, const float* Win, const float* Wnode,
    const float* bcc, const float* bnode, const float* bcs, const float* bin,
    const float* accv, const float* acsv,
    u16* wsu, float* wsf, int* cnts) {
  __shared__ float Ls[64 * 65];
  int b = blockIdx.x, t = threadIdx.x;
  if (b < NB_Z0) {                                 // ---- zero counters ----
    int i = b * 256 + t;
    if (i < 23268) ((int4*)cnts)[i] = make_int4(0, 0, 0, 0);
    return;
  }
  b -= NB_Z0;
  if (b < NB_FT) {                                 // ---- f32 -> bf16 feats ----
    const float* src; u16* dst; int idx, n4;
    if (b < 3750) {
      int ty = b / 1250;
      src = (ty == 0) ? f1 : (ty == 1) ? f2 : f3;
      dst = wsu + FBC + (size_t)ty * 1280000;
      idx = (b - ty * 1250) * 256 + t; n4 = 320000;
    } else {
      src = fs; dst = wsu + FBS; idx = (b - 3750) * 256 + t; n4 = 16384;
    }
    if (idx < n4) {
      float4 v = ((const float4*)src)[idx];
      uint2 o;
      o.x = (unsigned)f2b(v.x) | ((unsigned)f2b(v.y) << 16);
      o.y = (unsigned)f2b(v.z) | ((unsigned)f2b(v.w) << 16);
      *(uint2*)(dst + (size_t)idx * 4) = o;
    }
    return;
  }
  b -= NB_FT;
  if (b < NB_WT) {                                 // ---- weight transpose, LDS tile ----
    int mat = b >> 3, sub = b & 7;                 // mat 0..12
    int K = (mat == 12) ? INS : INC;
    if (mat == 12 && sub >= 4) return;
    int k0 = (sub >> 2) * 64, n0 = (sub & 3) * 64;
    const float* src; u16* dst;
    if (mat < 9)        { src = Wcc + (size_t)mat * INC * HD;        dst = wsu + WTCC + (size_t)mat * 32768; }
    else if (mat < 12)  { src = Wcs + (size_t)(mat - 9) * INC * HD;  dst = wsu + WTCS + (size_t)(mat - 9) * 32768; }
    else                { src = Win;                                 dst = wsu + WTIN; }
    #pragma unroll
    for (int it = 0; it < 4; it++) {
      int idx = t + it * 256;
      int r = idx >> 4, c4 = idx & 15;
      float4 v = *(const float4*)&src[(size_t)(k0 + r) * HD + n0 + c4 * 4];
      Ls[r * 65 + c4 * 4 + 0] = v.x; Ls[r * 65 + c4 * 4 + 1] = v.y;
      Ls[r * 65 + c4 * 4 + 2] = v.z; Ls[r * 65 + c4 * 4 + 3] = v.w;
    }
    __syncthreads();
    int n = t >> 2, k8 = (t & 3) * 16;
    unsigned o[8];
    #pragma unroll
    for (int j = 0; j < 8; j++) {
      u16 lo = f2b(Ls[(k8 + 2 * j) * 65 + n]);
      u16 hi = f2b(Ls[(k8 + 2 * j + 1) * 65 + n]);
      o[j] = (unsigned)lo | ((unsigned)hi << 16);
    }
    uint4* dp = (uint4*)&dst[(size_t)(n0 + n) * K + k0 + k8];
    dp[0] = make_uint4(o[0], o[1], o[2], o[3]);
    dp[1] = make_uint4(o[4], o[5], o[6], o[7]);
    return;
  }
  b -= NB_WT;                                      // ---- attn fold: 4 tiles x 8 groups ----
  int tile = b >> 3, sub = b & 7;
  int K = (tile == 3) ? INS : INC;
  int c0 = sub * 8;
  for (int idx = t; idx < 8 * K; idx += 256) {
    int col = c0 + idx / K, k = idx % K;
    int m = col >> 3, h = col & 7;
    const float* W = nullptr; const float* av = nullptr;
    if (tile < 3) {
      if (m < 3)      { int r = 3*tile + m; W = Wcc + (size_t)r*INC*HD;   av = accv + (size_t)r*512 + h*32; }
      else if (m < 6) { int r = 3*(m-3) + tile; W = Wnode + (size_t)tile*INC*HD; av = accv + (size_t)r*512 + 256 + h*32; }
      else if (m == 6){ W = Wcs + (size_t)tile*INC*HD; av = acsv + (size_t)tile*512 + h*32; }
    } else if (m < 3) { W = Win; av = acsv + (size_t)m*512 + 256 + h*32; }
    float s = 0.f;
    if (W) {
      const float* wp = W + (size_t)k * HD + h * 32;
      #pragma unroll 8
      for (int d = 0; d < 32; d++) s += wp[d] * av[d];
    }
    wsu[WAT + (size_t)tile * 8192 + (size_t)col * K + k] = f2b(s);
  }
  if (sub == 0 && t < 64) {
    int col = t, m = col >> 3, h = col & 7;
    const float* bb = nullptr; const float* av = nullptr;
    if (tile < 3) {
      if (m < 3)      { int r = 3*tile + m; bb = bcc + (size_t)r*HD;  av = accv + (size_t)r*512 + h*32; }
      else if (m < 6) { int r = 3*(m-3) + tile; bb = bnode + (size_t)tile*HD; av = accv + (size_t)r*512 + 256 + h*32; }
      else if (m == 6){ bb = bcs + (size_t)tile*HD; av = acsv + (size_t)tile*512 + h*32; }
    } else if (m < 3) { bb = bin; av = acsv + (size_t)m*512 + 256 + h*32; }
    float s = 0.f;
    if (bb) for (int d = 0; d < 32; d++) s += bb[h*32 + d] * av[d];
    wsf[BAF + tile * 64 + col] = s;
  }
}

// ================= K2: interleaved scatter (1 of 5) + GEMMs =================
__global__ __launch_bounds__(256, 2) void k_fuse(
    u16* wsu, float* wsf, const float* bcc, const float* bcs, const float* bin,
    const int* eccs, const int* eccd, const int* ecss, const int* ecsd,
    int* cnts, u16* slt) {
  __shared__ __align__(16) char smem[69632];
  int gb = blockIdx.x, t = threadIdx.x;
  if ((gb % 5) == 4) {                             // ---- edge scatter, 8/thread ----
    int k = gb / 5;                                // 0..541
    int i0 = (k * 256 + t) * 8;
    if (i0 >= TOTE) return;
    int dd[8], ss[8], p[8];
    int cbase;
    if (i0 < 9 * ECC) {
      int r = i0 / ECC;
      int4 d0 = *(const int4*)&eccd[i0]; int4 d1 = *(const int4*)&eccd[i0 + 4];
      int4 s0 = *(const int4*)&eccs[i0]; int4 s1 = *(const int4*)&eccs[i0 + 4];
      dd[0]=d0.x; dd[1]=d0.y; dd[2]=d0.z; dd[3]=d0.w;
      dd[4]=d1.x; dd[5]=d1.y; dd[6]=d1.z; dd[7]=d1.w;
      ss[0]=s0.x; ss[1]=s0.y; ss[2]=s0.z; ss[3]=s0.w;
      ss[4]=s1.x; ss[5]=s1.y; ss[6]=s1.z; ss[7]=s1.w;
      cbase = r * NC;
    } else {
      int u0 = i0 - 9 * ECC;
      int r = u0 / ECS;
      int4 d0 = *(const int4*)&ecsd[u0]; int4 d1 = *(const int4*)&ecsd[u0 + 4];
      int4 s0 = *(const int4*)&ecss[u0]; int4 s1 = *(const int4*)&ecss[u0 + 4];
      dd[0]=d0.x; dd[1]=d0.y; dd[2]=d0.z; dd[3]=d0.w;
      dd[4]=d1.x; dd[5]=d1.y; dd[6]=d1.z; dd[7]=d1.w;
      ss[0]=s0.x; ss[1]=s0.y; ss[2]=s0.z; ss[3]=s0.w;
      ss[4]=s1.x; ss[5]=s1.y; ss[6]=s1.z; ss[7]=s1.w;
      cbase = 90000 + r * NS;
    }
    #pragma unroll
    for (int q = 0; q < 8; q++) p[q] = atomicAdd(&cnts[cbase + dd[q]], 1);
    #pragma unroll
    for (int q = 0; q < 8; q++)
      if (p[q] < CAP) slt[((size_t)(cbase + dd[q])) * CAP + p[q]] = (u16)ss[q];
    return;
  }
  int g = 4 * (gb / 5) + (gb % 5);                 // gemm id 0..2167
  if (g >= 2157) return;
  u16* As = (u16*)smem;
  u16* Bs = (u16*)(smem + 34816);
  const u16 *A, *Bt; const float* bias = nullptr; u16* C = nullptr;
  int M, K, r0, n0 = 0, ty = 0;
  bool isScore = false;
  if (g < 1896) {
    int z = g / 158, rem = g - z * 158;
    int by = rem / 79, bx = rem - by * 79;
    r0 = bx * 128; n0 = by * 128; M = NC; K = 128;
    if (z < 9) { A = wsu + FBC + (size_t)(z/3)*1280000; Bt = wsu + WTCC + (size_t)z*32768; bias = bcc + (size_t)z*HD; C = wsu + WHB_CC + (size_t)z*NC*HD; }
    else { int q = z - 9; A = wsu + FBC + (size_t)q*1280000; Bt = wsu + WTCS + (size_t)q*32768; bias = bcs + (size_t)q*HD; C = wsu + WHB_CS + (size_t)q*NC*HD; }
  } else if (g < 1912) {
    int loc = g - 1896; int by = loc / 8, bx = loc - by * 8;
    r0 = bx * 128; n0 = by * 128; M = NS; K = 64;
    A = wsu + FBS; Bt = wsu + WTIN; bias = bin; C = wsu + WHB_IN;
  } else if (g < 2149) {
    isScore = true; ty = (g - 1912) / 79; int bx = (g - 1912) % 79;
    r0 = bx * 128; M = NC; K = 128;
    A = wsu + FBC + (size_t)ty * 1280000; Bt = wsu + WAT + (size_t)ty * 8192;
  } else {
    isScore = true; ty = 3; int bx = g - 2149;
    r0 = bx * 128; M = NS; K = 64;
    A = wsu + FBS; Bt = wsu + WAT + (size_t)3 * 8192;
  }
  int SA = K + 8;
  int NB = isScore ? 64 : 128;
  {
    int ksh = (K == 128) ? 4 : 3;
    int kmask = (1 << ksh) - 1;
    int sc8 = SA >> 3;
    const uint4* ga = (const uint4*)(A + (size_t)r0 * K);
    const uint4* gb2 = (const uint4*)(Bt + (size_t)n0 * K);
    uint4* la = (uint4*)As; uint4* lb = (uint4*)Bs;
    int tota = (128 * K) >> 3, totb = (NB * K) >> 3;
    for (int i = t; i < tota; i += 256) la[(i >> ksh) * sc8 + (i & kmask)] = ga[i];
    for (int i = t; i < totb; i += 256) lb[(i >> ksh) * sc8 + (i & kmask)] = gb2[i];
  }
  __syncthreads();
  int lane = t & 63, w = t >> 6, l16 = lane & 15, quad = lane >> 4;
  int arow0 = w * 32 + l16;
  if (!isScore) {
    f32x4 acc[2][8];
    #pragma unroll
    for (int i = 0; i < 2; i++)
      #pragma unroll
      for (int j = 0; j < 8; j++) acc[i][j] = (f32x4){0.f, 0.f, 0.f, 0.f};
    for (int ks = 0; ks < K; ks += 32) {
      int ko = ks + quad * 8;
      short8 a0 = *(const short8*)&As[(size_t)arow0 * SA + ko];
      short8 a1 = *(const short8*)&As[(size_t)(arow0 + 16) * SA + ko];
      #pragma unroll
      for (int j = 0; j < 8; j++) {
        short8 bfr = *(const short8*)&Bs[(size_t)(j * 16 + l16) * SA + ko];
        acc[0][j] = __builtin_amdgcn_mfma_f32_16x16x32_bf16(a0, bfr, acc[0][j], 0, 0, 0);
        acc[1][j] = __builtin_amdgcn_mfma_f32_16x16x32_bf16(a1, bfr, acc[1][j], 0, 0, 0);
      }
    }
    __syncthreads();
    float* Cl = (float*)smem;            // 128 x 132 (2-way = free)
    #pragma unroll
    for (int i = 0; i < 2; i++) {
      int rl0 = w * 32 + i * 16 + quad * 4;
      #pragma unroll
      for (int j = 0; j < 8; j++) {
        int cl = j * 16 + l16;
        float bv = bias[n0 + cl];
        #pragma unroll
        for (int rg = 0; rg < 4; rg++)
          Cl[(rl0 + rg) * 132 + cl] = acc[i][j][rg] + bv;
      }
    }
    __syncthreads();
    for (int task = t; task < 2048; task += 256) {
      int row = task >> 4, seg = task & 15;
      int gr = r0 + row;
      if (gr >= M) continue;
      const float* cp = Cl + row * 132 + seg * 8;
      float4 v0 = *(const float4*)cp;
      float4 v1 = *(const float4*)(cp + 4);
      uint4 o;
      o.x = (unsigned)f2b(v0.x) | ((unsigned)f2b(v0.y) << 16);
      o.y = (unsigned)f2b(v0.z) | ((unsigned)f2b(v0.w) << 16);
      o.z = (unsigned)f2b(v1.x) | ((unsigned)f2b(v1.y) << 16);
      o.w = (unsigned)f2b(v1.z) | ((unsigned)f2b(v1.w) << 16);
      *(uint4*)&C[(size_t)gr * HD + n0 + seg * 8] = o;
    }
  } else {
    f32x4 acc[2][4];
    #pragma unroll
    for (int i = 0; i < 2; i++)
      #pragma unroll
      for (int j = 0; j < 4; j++) acc[i][j] = (f32x4){0.f, 0.f, 0.f, 0.f};
    for (int ks = 0; ks < K; ks += 32) {
      int ko = ks + quad * 8;
      short8 a0 = *(const short8*)&As[(size_t)arow0 * SA + ko];
      short8 a1 = *(const short8*)&As[(size_t)(arow0 + 16) * SA + ko];
      #pragma unroll
      for (int j = 0; j < 4; j++) {
        short8 bfr = *(const short8*)&Bs[(size_t)(j * 16 + l16) * SA + ko];
        acc[0][j] = __builtin_amdgcn_mfma_f32_16x16x32_bf16(a0, bfr, acc[0][j], 0, 0, 0);
        acc[1][j] = __builtin_amdgcn_mfma_f32_16x16x32_bf16(a1, bfr, acc[1][j], 0, 0, 0);
      }
    }
    float* sp[4]; float bav[4];
    #pragma unroll
    for (int j = 0; j < 4; j++) {
      int col = j * 16 + l16;
      int m = col >> 3, h = col & 7;
      float* p = nullptr;
      if (ty < 3) {
        if (m < 3)       p = wsf + ASCC + (size_t)(3*ty + m) * NC * H_;
        else if (m < 6)  p = wsf + ADCC + (size_t)(3*(m-3) + ty) * NC * H_;
        else if (m == 6) p = wsf + ASCS + (size_t)ty * NC * H_;
      } else if (m < 3)  p = wsf + ADCS + (size_t)m * NS * H_;
      sp[j] = p ? (p + h) : nullptr;
      bav[j] = wsf[BAF + ty * 64 + col];
    }
    #pragma unroll
    for (int i = 0; i < 2; i++) {
      int rl0 = w * 32 + i * 16 + quad * 4;
      #pragma unroll
      for (int j = 0; j < 4; j++) {
        if (!sp[j]) continue;
        #pragma unroll
        for (int rg = 0; rg < 4; rg++) {
          int gr = r0 + rl0 + rg;
          // pre-scale by log2(e) so k_agg does exp2 directly (lrelu commutes
          // with a positive scale).
          if (gr < M) sp[j][(size_t)gr * 8] = (acc[i][j][rg] + bav[j]) * 1.44269504089f;
        }
      }
    }
  }
}

// ================= K3: aggregation (R11 structure + XCD chunk swizzle) =================
// 1 wave/dst node, 8-edge groups, VGPR 32 / occ ~70% (R11-proven).
// Block swizzle: nwg = 7756 = 8*969 + 4. Assuming round-robin wg->XCD
// (orig % 8), remap so XCD i owns a CONTIGUOUS node range -> its L2 holds
// only its dtype's 3-4 message pools instead of all 12.
__global__ __launch_bounds__(256) void k_agg(const u16* wsu, const float* wsf,
                                             const int* cnts, const u16* slt,
                                             float* out) {
  int t = threadIdx.x, lane = t & 63, w = t >> 6;
  // bijective XCD-chunk swizzle (m204): q=969, r=4
  int borig = blockIdx.x;
  int xcd = borig & 7, pos = borig >> 3;
  int sb = (xcd < 4) ? xcd * 970 + pos : 3880 + (xcd - 4) * 969 + pos;
  int node = sb * 4 + w;
  int l3 = lane >> 3, h7 = lane & 7;
  int lb = lane * 8;                               // byte offset in 512B msg row
  f32x2 totA = {0.f, 0.f}, totB = {0.f, 0.f};
  bool isC = node < 3 * NC;
  int dtype = 0, n;
  if (isC) { dtype = node / NC; n = node - dtype * NC; } else { n = node - 3 * NC; }
  for (int j = 0; j < 3; j++) {
    int cidx; const float* ASp; const float* ADp; const char* wb;
    if (isC) {
      int r = j * 3 + dtype;
      cidx = r * NC + n;
      ASp = wsf + ASCC + (size_t)r * NC * H_;
      ADp = wsf + ADCC + (size_t)r * NC * H_;
      wb  = (const char*)(wsu + WHB_CC + (size_t)r * NC * HD);
    } else {
      cidx = 90000 + j * NS + n;
      ASp = wsf + ASCS + (size_t)j * NC * H_;
      ADp = wsf + ADCS + (size_t)j * NS * H_;
      wb  = (const char*)(wsu + WHB_CS + (size_t)j * NC * HD);
    }
    int cnt = min(cnts[cidx], CAP);
    if (cnt <= 0) continue;
    int srcid = (int)slt[(size_t)cidx * CAP + min(lane, cnt - 1)];
    float adn = ADp[(size_t)n * H_ + h7];
    f32x2 aA = {0.f, 0.f}, aB = {0.f, 0.f};
    float zac = 0.f;
    // score for group 0 (scores pre-scaled by log2e in k_fuse -> exp2 only)
    float wcur;
    {
      int ce = min(l3, cnt - 1);
      int sid = __shfl(srcid, ce);
      float sc = ASp[(size_t)sid * H_ + h7] + adn;
      sc = fmaxf(sc, ALPHA * sc);
      wcur = (l3 < cnt) ? __builtin_amdgcn_exp2f(sc) : 0.f;
    }
    for (int g = 0; g < cnt; g += 8) {
      uint2 mreg[8];
      #pragma unroll
      for (int ee = 0; ee < 8; ee++) {
        int ce = min(g + ee, cnt - 1);                       // wave-uniform
        int sre = __builtin_amdgcn_readlane(srcid, ce);      // SGPR row id
        mreg[ee] = *(const uint2*)(wb + ((size_t)(unsigned)sre << 9) + lb);
      }
      float wold = wcur;
      zac += wold;
      if (g + 8 < cnt) {                                     // prefetch next score
        int e = g + 8 + l3;
        int ce = min(e, cnt - 1);
        int sid = __shfl(srcid, ce);
        float sc = ASp[(size_t)sid * H_ + h7] + adn;
        sc = fmaxf(sc, ALPHA * sc);
        wcur = (e < cnt) ? __builtin_amdgcn_exp2f(sc) : 0.f;
      }
      #pragma unroll
      for (int ee = 0; ee < 8; ee++) {
        float we = __shfl(wold, ee * 8 + l3);
        f32x2 q0, q1;
        q0.x = bl(mreg[ee].x); q0.y = bh(mreg[ee].x);
        q1.x = bl(mreg[ee].y); q1.y = bh(mreg[ee].y);
        aA += q0 * we;
        aB += q1 * we;
      }
    }
    // Z[h]: sum w over the 8 e-slots (bits 3..5), then broadcast to payload h
    zac += __shfl_xor(zac, 8);
    zac += __shfl_xor(zac, 16);
    zac += __shfl_xor(zac, 32);
    float inv = 1.f / zac;
    float invp = __shfl(inv, l3);
    totA += aA * invp;
    totB += aB * invp;
  }
  if (!isC) {                                                // state self term
    uint2 m = *(const uint2*)((const char*)(wsu + WHB_IN) + (size_t)n * 512 + lb);
    totA.x += bl(m.x); totA.y += bh(m.x);
    totB.x += bl(m.y); totB.y += bh(m.y);
  }
  float4 v = make_float4(fmaxf(totA.x, 0.f), fmaxf(totA.y, 0.f),
                         fmaxf(totB.x, 0.f), fmaxf(totB.y, 0.f));
  *(float4*)(out + (size_t)node * HD + lane * 4) = v;
}

extern "C" void kernel_launch(void* const* d_in, const int* in_sizes, int n_in,
                              void* d_out, int out_size, void* d_ws, size_t ws_size,
                              hipStream_t stream) {
  (void)in_sizes; (void)n_in; (void)out_size; (void)ws_size;
  const float* f1    = (const float*)d_in[0];
  const float* f2    = (const float*)d_in[1];
  const float* f3    = (const float*)d_in[2];
  const float* fs    = (const float*)d_in[3];
  const float* Wnode = (const float*)d_in[4];
  const float* bnode = (const float*)d_in[5];
  const float* Wcc   = (const float*)d_in[6];
  const float* bcc   = (const float*)d_in[7];
  const float* Wcs   = (const float*)d_in[8];
  const float* bcs   = (const float*)d_in[9];
  const float* Win   = (const float*)d_in[10];
  const float* bin   = (const float*)d_in[11];
  const float* accv  = (const float*)d_in[12];
  const float* acsv  = (const float*)d_in[13];
  const int* eccs    = (const int*)d_in[14];
  const int* eccd    = (const int*)d_in[15];
  const int* ecss    = (const int*)d_in[16];
  const int* ecsd    = (const int*)d_in[17];
  float* wsf = (float*)d_ws;
  u16*   wsu = (u16*)d_ws;
  int*   cnts = (int*)((char*)d_ws + IBYTE);
  u16*   slt  = (u16*)((char*)d_ws + SBYTE);
  float* out = (float*)d_out;

  k_prep<<<dim3(NB_Z0 + NB_FT + NB_WT + NB_FO), 256, 0, stream>>>(
      f1, f2, f3, fs, Wcc, Wcs, Win, Wnode, bcc, bnode, bcs, bin, accv, acsv,
      wsu, wsf, cnts);
  k_fuse<<<dim3(NB_K2), 256, 0, stream>>>(
      wsu, wsf, bcc, bcs, bin, eccs, eccd, ecss, ecsd, cnts, slt);
  k_agg<<<dim3((3 * NC + NS) / 4), 256, 0, stream>>>(wsu, wsf, cnts, slt, out);
}